// Round 1
// baseline (136.785 us; speedup 1.0000x reference)
//
#include <hip/hip_runtime.h>

// LSA fused kernel: out = fmap + gamma * (Wv @ s), s[k,n] = sum_l attn[n,l]*fmap[k,nbr(n,l)]
// Reordering is exact (linearity): window-gather commutes with the 1x1 conv.
// B=4, C=128, H=64, W=128, 5x5 window (replicate pad), HEADS=1.

namespace {
constexpr int Bn = 4, Cn = 128, Hn = 64, Wn = 128, Ln = 25;
constexpr int TH = 8, TW = 8;          // pixel tile per block
constexpr int HR = TH + 4, HC = TW + 4; // halo tile (12x12)
constexpr int KC = 16;                  // k-chunk
constexpr int NT = 256;                 // threads per block
constexpr int HWn = Hn * Wn;

__global__ __launch_bounds__(NT) void lsa_fused(
    const float* __restrict__ attn,   // [B][1][H*W][25]
    const float* __restrict__ fmap,   // [B][C][H][W]
    const float* __restrict__ Wv,     // [C][C]
    const float* __restrict__ gamma,  // [1]
    float* __restrict__ out)          // [B][C][H][W]
{
    __shared__ float attn_s[TH * TW * Ln];   // [p][l], 6.4 KB
    __shared__ float fm_s[KC][HR * HC];      // [k][halo_px], 9.2 KB
    __shared__ float wv_s[Cn][KC];           // [c][k], 8 KB (rows 64B -> aligned f4)
    __shared__ float s_s[KC][TH * TW];       // [k][p], 4 KB

    const int tid = threadIdx.x;
    const int x0 = blockIdx.x * TW;
    const int y0 = blockIdx.y * TH;
    const int b  = blockIdx.z;
    const float g = gamma[0];

    // ---- stage attn tile: [64 px][25] ----
    for (int i = tid; i < TH * TW * Ln; i += NT) {
        int p = i / Ln, l = i - p * Ln;
        int n = (y0 + (p >> 3)) * Wn + x0 + (p & 7);
        attn_s[i] = attn[((size_t)b * HWn + n) * Ln + l];
    }
    __syncthreads();

    // s-phase mapping: p fixed per thread, 4 k-values per chunk
    const int sp = tid & 63;        // pixel 0..63
    const int ksub = tid >> 6;      // 0..3
    float a[Ln];
#pragma unroll
    for (int l = 0; l < Ln; ++l) a[l] = attn_s[sp * Ln + l];
    const int fbase = (sp >> 3) * HC + (sp & 7);

    // GEMM mapping: thread owns 8 channels x 4 pixels
    const int pg = tid & 15;        // pixel group: px pg*4 .. pg*4+3
    const int cg = tid >> 4;        // channel group: ch cg*8 .. cg*8+7
    float4 acc[8];
#pragma unroll
    for (int cc = 0; cc < 8; ++cc) acc[cc] = make_float4(0.f, 0.f, 0.f, 0.f);

    for (int kc = 0; kc < Cn; kc += KC) {
        __syncthreads();  // protect fm_s/wv_s/s_s reuse vs previous iteration readers

        // stage fmap halo chunk (replicate-clamped)
        for (int i = tid; i < KC * HR * HC; i += NT) {
            int k  = i / (HR * HC), hp = i - k * (HR * HC);
            int hy = hp / HC, hx = hp - hy * HC;
            int gy = y0 + hy - 2; gy = gy < 0 ? 0 : (gy > Hn - 1 ? Hn - 1 : gy);
            int gx = x0 + hx - 2; gx = gx < 0 ? 0 : (gx > Wn - 1 ? Wn - 1 : gx);
            fm_s[k][hp] = fmap[((size_t)(b * Cn + kc + k) * Hn + gy) * Wn + gx];
        }
        // stage Wv chunk [128 c][16 k]
        for (int i = tid; i < Cn * KC; i += NT) {
            int c = i >> 4, k = i & 15;
            wv_s[c][k] = Wv[(size_t)c * Cn + kc + k];
        }
        __syncthreads();

        // ---- s phase: s[k][p] = sum_l attn[p][l] * fmap_halo[k][p + off(l)] ----
#pragma unroll
        for (int ki = 0; ki < KC / 4; ++ki) {
            int k = ksub + ki * 4;
            float s = 0.f;
#pragma unroll
            for (int l = 0; l < Ln; ++l) {
                int di = l / 5, dj = l - di * 5;
                s += a[l] * fm_s[k][fbase + di * HC + dj];
            }
            s_s[k][sp] = s;
        }
        __syncthreads();

        // ---- GEMM accumulate: acc[c][p] += Wv[c][k] * s[k][p] ----
#pragma unroll
        for (int k4 = 0; k4 < KC / 4; ++k4) {
            float4 sv0 = *(const float4*)&s_s[k4 * 4 + 0][pg * 4];
            float4 sv1 = *(const float4*)&s_s[k4 * 4 + 1][pg * 4];
            float4 sv2 = *(const float4*)&s_s[k4 * 4 + 2][pg * 4];
            float4 sv3 = *(const float4*)&s_s[k4 * 4 + 3][pg * 4];
#pragma unroll
            for (int cc = 0; cc < 8; ++cc) {
                float4 wv = *(const float4*)&wv_s[cg * 8 + cc][k4 * 4];
                acc[cc].x += wv.x * sv0.x + wv.y * sv1.x + wv.z * sv2.x + wv.w * sv3.x;
                acc[cc].y += wv.x * sv0.y + wv.y * sv1.y + wv.z * sv2.y + wv.w * sv3.y;
                acc[cc].z += wv.x * sv0.z + wv.y * sv1.z + wv.z * sv2.z + wv.w * sv3.z;
                acc[cc].w += wv.x * sv0.w + wv.y * sv1.w + wv.z * sv2.w + wv.w * sv3.w;
            }
        }
    }

    // ---- epilogue: out = fmap + gamma * acc ----
    const int gy = y0 + (pg >> 1);
    const int gx = x0 + (pg & 1) * 4;
#pragma unroll
    for (int cc = 0; cc < 8; ++cc) {
        int c = cg * 8 + cc;
        size_t idx = ((size_t)(b * Cn + c) * Hn + gy) * Wn + gx;
        float4 f = *(const float4*)&fmap[idx];
        float4 o;
        o.x = f.x + g * acc[cc].x;
        o.y = f.y + g * acc[cc].y;
        o.z = f.z + g * acc[cc].z;
        o.w = f.w + g * acc[cc].w;
        *(float4*)&out[idx] = o;
    }
}
}  // namespace

extern "C" void kernel_launch(void* const* d_in, const int* in_sizes, int n_in,
                              void* d_out, int out_size, void* d_ws, size_t ws_size,
                              hipStream_t stream) {
    const float* attn  = (const float*)d_in[0];
    const float* fmap  = (const float*)d_in[1];
    const float* Wv    = (const float*)d_in[2];
    const float* gamma = (const float*)d_in[3];
    float* out = (float*)d_out;

    dim3 grid(Wn / TW, Hn / TH, Bn);   // 16 x 8 x 4 = 512 blocks
    lsa_fused<<<grid, NT, 0, stream>>>(attn, fmap, Wv, gamma, out);
}

// Round 2
// 116.575 us; speedup vs baseline: 1.1734x; 1.1734x over previous
//
#include <hip/hip_runtime.h>

// LSA split into two kernels (linearity: out = fmap + g * Wv @ s,
//   s[k,n] = sum_l attn[n,l] * fmap[k, nbr(n,l)]):
//  K1: stencil -> sT[b][n][k] bf16 (pixel-major, k-contiguous) + Wv->bf16, into d_ws
//  K2: MFMA bf16 GEMM (M=C=128, N=pixels, K=128) + residual, no LDS/barriers.
// B=4, C=128, H=64, W=128, 5x5 window replicate pad.

namespace {
constexpr int Bn = 4, Cn = 128, Hn = 64, Wn = 128, Ln = 25;
constexpr int HWn = Hn * Wn;  // 8192

__device__ inline unsigned short f2bf(float f) {
    unsigned u = __float_as_uint(f);
    unsigned r = (u + 0x7fffu + ((u >> 16) & 1u)) >> 16;  // RNE
    return (unsigned short)r;
}

// ---------------- K1: stencil ----------------
constexpr int TH = 4, TW = 16, TP = TH * TW;   // 64 px per block
constexpr int HR = TH + 4, HC = TW + 4;        // 8 x 20 halo
constexpr int HP = HR * HC;                    // 160
constexpr int KC = 32;                         // k-chunk
constexpr int FMPAD = 36;                      // fm row stride (floats), 16B-aligned rows
constexpr int STPAD = TP + 1;                  // 65

__global__ __launch_bounds__(256) void lsa_stencil(
    const float* __restrict__ attn, const float* __restrict__ fmap,
    const float* __restrict__ Wv,
    unsigned short* __restrict__ sT, unsigned short* __restrict__ wvb)
{
    __shared__ float fm_s[HP * FMPAD];   // [halo_px][k] 23.0 KB
    __shared__ float st[64 * STPAD];     // [k-in-pair][px] 16.6 KB

    const int tid = threadIdx.x;
    const int x0 = blockIdx.x * TW, y0 = blockIdx.y * TH;
    const int b = blockIdx.z;

    // one block also converts Wv to bf16 (rewritten every call; ws is re-poisoned)
    if (blockIdx.x == 0 && blockIdx.y == 0 && b == 0) {
        for (int i = tid; i < Cn * Cn; i += 256) wvb[i] = f2bf(Wv[i]);
    }

    const int px = tid & 63, ksub = tid >> 6;  // 64 px x 4 k-subgroups
    const int x = px & 15, y = px >> 4;
    const int n = (y0 + y) * Wn + x0 + x;
    float a[Ln];
#pragma unroll
    for (int l = 0; l < Ln; ++l) a[l] = attn[((size_t)b * HWn + n) * Ln + l];
    const int fb = y * HC + x;  // halo base; l adds (l/5)*HC + l%5

    for (int cp = 0; cp < 2; ++cp) {        // chunk-pair: 64 k
        for (int half = 0; half < 2; ++half) {
            const int kc = cp * 64 + half * KC;
            __syncthreads();  // st/fm_s consumers from previous phase done
            // stage fmap halo chunk, transposed to [hp][k]
            for (int i = tid; i < KC * HP; i += 256) {
                int k = i / HP, hp = i - k * HP;
                int hy = hp / HC, hx = hp - hy * HC;
                int gy = y0 + hy - 2; gy = min(max(gy, 0), Hn - 1);
                int gx = x0 + hx - 2; gx = min(max(gx, 0), Wn - 1);
                fm_s[hp * FMPAD + k] = fmap[((size_t)(b * Cn + kc + k) * Hn + gy) * Wn + gx];
            }
            __syncthreads();
            // each thread: 8 channels (2 x float4) for its pixel
#pragma unroll
            for (int k4 = 0; k4 < 2; ++k4) {
                const int ko = ksub * 8 + k4 * 4;
                float4 acc = make_float4(0.f, 0.f, 0.f, 0.f);
#pragma unroll
                for (int l = 0; l < Ln; ++l) {
                    const float4 f = *(const float4*)&fm_s[(fb + (l / 5) * HC + (l % 5)) * FMPAD + ko];
                    acc.x += a[l] * f.x; acc.y += a[l] * f.y;
                    acc.z += a[l] * f.z; acc.w += a[l] * f.w;
                }
                const int kr = half * KC + ko;
                st[(kr + 0) * STPAD + px] = acc.x;
                st[(kr + 1) * STPAD + px] = acc.y;
                st[(kr + 2) * STPAD + px] = acc.z;
                st[(kr + 3) * STPAD + px] = acc.w;
            }
        }
        __syncthreads();
        // writeout chunk-pair: 64 k x 64 px -> bf16 pairs, k-contiguous global
        for (int i = tid; i < 2048; i += 256) {
            int pr = i & 31, p2 = i >> 5;
            float lo = st[(2 * pr) * STPAD + p2];
            float hi = st[(2 * pr + 1) * STPAD + p2];
            int nn = (y0 + (p2 >> 4)) * Wn + x0 + (p2 & 15);
            unsigned val = (unsigned)f2bf(lo) | ((unsigned)f2bf(hi) << 16);
            *(unsigned*)&sT[((size_t)b * HWn + nn) * Cn + cp * 64 + 2 * pr] = val;
        }
    }
}

// ---------------- K2: MFMA GEMM + residual ----------------
typedef __attribute__((ext_vector_type(8))) short short8;
typedef __attribute__((ext_vector_type(4))) float f32x4;

__global__ __launch_bounds__(256) void lsa_gemm(
    const unsigned short* __restrict__ sT, const unsigned short* __restrict__ wvb,
    const float* __restrict__ fmap, const float* __restrict__ gamma,
    float* __restrict__ out)
{
    const int tid = threadIdx.x;
    const int wave = tid >> 6, lane = tid & 63;
    const int m16 = lane & 15, q = lane >> 4;
    const int b = blockIdx.y;
    const int ntile = blockIdx.x * 32 + (wave >> 1) * 16;  // 16 px per wave
    const int mhalf = wave & 1;                            // 64 channels per wave
    const float g = gamma[0];

    // B fragments (k-runs are contiguous in sT's pixel-major layout)
    short8 bfrag[4];
    const unsigned short* srow = &sT[((size_t)b * HWn + ntile + m16) * Cn + q * 8];
#pragma unroll
    for (int kk = 0; kk < 4; ++kk) bfrag[kk] = *(const short8*)(srow + kk * 32);

    f32x4 acc[4];
#pragma unroll
    for (int t = 0; t < 4; ++t) { f32x4 z = {0.f, 0.f, 0.f, 0.f}; acc[t] = z; }

#pragma unroll
    for (int t = 0; t < 4; ++t) {
        const int mg = mhalf * 4 + t;
        const unsigned short* arow = &wvb[(size_t)(mg * 16 + m16) * Cn + q * 8];
#pragma unroll
        for (int kk = 0; kk < 4; ++kk) {
            short8 af = *(const short8*)(arow + kk * 32);
            acc[t] = __builtin_amdgcn_mfma_f32_16x16x32_bf16(af, bfrag[kk], acc[t], 0, 0, 0);
        }
    }

    // epilogue: D row=(lane>>4)*4+r (channel), col=lane&15 (pixel)
#pragma unroll
    for (int t = 0; t < 4; ++t) {
        const int mg = mhalf * 4 + t;
#pragma unroll
        for (int r = 0; r < 4; ++r) {
            const int c = mg * 16 + q * 4 + r;
            const size_t idx = ((size_t)(b * Cn + c)) * HWn + ntile + m16;
            out[idx] = fmap[idx] + g * acc[t][r];
        }
    }
}
}  // namespace

extern "C" void kernel_launch(void* const* d_in, const int* in_sizes, int n_in,
                              void* d_out, int out_size, void* d_ws, size_t ws_size,
                              hipStream_t stream) {
    const float* attn  = (const float*)d_in[0];
    const float* fmap  = (const float*)d_in[1];
    const float* Wv    = (const float*)d_in[2];
    const float* gamma = (const float*)d_in[3];
    float* out = (float*)d_out;

    unsigned short* sT  = (unsigned short*)d_ws;                       // 8.39 MB
    unsigned short* wvb = (unsigned short*)((char*)d_ws + (size_t)Bn * HWn * Cn * 2);  // 32 KB

    dim3 g1(Wn / TW, Hn / TH, Bn);   // 8 x 16 x 4 = 512 blocks
    lsa_stencil<<<g1, 256, 0, stream>>>(attn, fmap, Wv, sT, wvb);

    dim3 g2(HWn / 32, Bn);           // 256 x 4 = 1024 blocks
    lsa_gemm<<<g2, 256, 0, stream>>>(sT, wvb, fmap, gamma, out);
}

// Round 4
// 111.709 us; speedup vs baseline: 1.2245x; 1.0436x over previous
//
#include <hip/hip_runtime.h>

// LSA pipeline from HW-verified pieces (R2 passed; R3's swizzled rewrite did not):
//   K_T : fmap[b][c][hw] f32 -> fT[b][n][c] bf16 (classic LDS tile transpose)
//         + wvb = bf16(Wv) folded into block 0 (R2-verified fold pattern)
//   K_ST: sT[b][n][k] = sum_l attn[n][l] * fT[nbr(n,l)][k]   (5x5 replicate-pad
//         stencil; halo stages as contiguous row-runs -- no transpose, 1 barrier)
//   K_V : out = fmap + gamma * Wv @ sT   (verbatim R2-K2 MFMA kernel, verified)
// B=4, C=128, H=64, W=128, L=25.

namespace {
constexpr int Bn = 4, Cn = 128, Hn = 64, Wn = 128, Ln = 25;
constexpr int HWn = Hn * Wn;  // 8192

typedef __attribute__((ext_vector_type(8))) short short8;
typedef __attribute__((ext_vector_type(4))) float f32x4;

__device__ inline unsigned short f2bf(float f) {
    unsigned u = __float_as_uint(f);
    return (unsigned short)((u + 0x7fffu + ((u >> 16) & 1u)) >> 16);  // RNE
}

// ---------------- K_T: transpose fmap -> fT (bf16), convert Wv ----------------
__global__ __launch_bounds__(256) void k_transpose(
    const float* __restrict__ fmap, const float* __restrict__ Wv,
    unsigned short* __restrict__ fT, unsigned short* __restrict__ wvb)
{
    __shared__ float tile[Cn][33];  // 32 px per block, +1 pad
    const int tid = threadIdx.x;
    const int b = blockIdx.y;
    const int n0 = blockIdx.x * 32;

    if (blockIdx.x == 0 && b == 0) {
        for (int i = tid; i < Cn * Cn; i += 256) wvb[i] = f2bf(Wv[i]);
    }
    // stage 128c x 32px, float4 along px (coalesced)
    for (int i = tid; i < Cn * 8; i += 256) {
        int c = i >> 3, q = i & 7;
        float4 v = *(const float4*)&fmap[((size_t)(b * Cn + c)) * HWn + n0 + q * 4];
        tile[c][q * 4 + 0] = v.x; tile[c][q * 4 + 1] = v.y;
        tile[c][q * 4 + 2] = v.z; tile[c][q * 4 + 3] = v.w;
    }
    __syncthreads();
    // write 32n x 64 channel-pairs (coalesced 256B per pixel row)
    for (int i = tid; i < 32 * 64; i += 256) {
        int n = i >> 6, cp = i & 63;
        unsigned lo = f2bf(tile[2 * cp][n]), hi = f2bf(tile[2 * cp + 1][n]);
        *(unsigned*)&fT[((size_t)(b * HWn + n0 + n)) * Cn + 2 * cp] = lo | (hi << 16);
    }
}

// ---------------- K_ST: 5x5 stencil on fT -> sT ----------------
constexpr int TY = 4, TX = 16;   // output tile
constexpr int HY = 8, HX = 24;   // halo rows x cols (x0-4 .. x0+19, y0-2 .. y0+5)
constexpr int RS = 136;          // halo row stride in halves (272B, 16B-aligned)

__global__ __launch_bounds__(256) void k_stencil(
    const unsigned short* __restrict__ fT, const float* __restrict__ attn,
    unsigned short* __restrict__ sT)
{
    __shared__ unsigned short hs[HY * HX * RS];  // 52.2 KB
    __shared__ float at_s[TY * TX * Ln];         // 6.4 KB
    const int tid = threadIdx.x;
    const int b = blockIdx.z;
    const int x0 = blockIdx.x * TX;
    const int y0 = blockIdx.y * TY;

    // stage halo: per (dy,hx) a contiguous 128-ch (256B) run; branch-free clamps
    for (int i = tid; i < HY * HX * 16; i += 256) {
        int dy = i / (HX * 16), r = i - dy * (HX * 16);
        int hx = r >> 4, t = r & 15;
        int ry = min(max(y0 + dy - 2, 0), Hn - 1);
        int gx = min(max(x0 + hx - 4, 0), Wn - 1);
        *(uint4*)&hs[(dy * HX + hx) * RS + t * 8] =
            *(const uint4*)&fT[((size_t)(b * HWn + ry * Wn + gx)) * Cn + t * 8];
    }
    // stage attn [p][l]
    for (int i = tid; i < TY * TX * Ln; i += 256) {
        int p = i / Ln, l = i - p * Ln;
        int n = (y0 + (p >> 4)) * Wn + x0 + (p & 15);
        at_s[i] = attn[((size_t)b * HWn + n) * Ln + l];
    }
    __syncthreads();

    // thread map: xi = tid&15, kq = (tid>>4)&3 (32-ch group), yi = tid>>6
    // (kq inside the wave spreads LDS banks: 4-way worst case)
    const int xi = tid & 15, kq = (tid >> 4) & 3, yi = tid >> 6;
    const int p = yi * 16 + xi;
    float acc[32];
#pragma unroll
    for (int j = 0; j < 32; ++j) acc[j] = 0.f;

#pragma unroll
    for (int l = 0; l < Ln; ++l) {
        const int dy = l / 5, dx = l % 5;
        const float a = at_s[p * Ln + l];
        const unsigned short* row = &hs[((yi + dy) * HX + (2 + xi + dx)) * RS + kq * 32];
#pragma unroll
        for (int q = 0; q < 4; ++q) {
            uint4 u = *(const uint4*)&row[q * 8];
            const unsigned w[4] = {u.x, u.y, u.z, u.w};
#pragma unroll
            for (int e = 0; e < 4; ++e) {
                float f0 = __uint_as_float(w[e] << 16);           // ch +2e   (lo half)
                float f1 = __uint_as_float(w[e] & 0xffff0000u);   // ch +2e+1 (hi half)
                acc[q * 8 + 2 * e + 0] += a * f0;
                acc[q * 8 + 2 * e + 1] += a * f1;
            }
        }
    }
    // write 32 bf16 (k-contiguous) for pixel (y0+yi, x0+xi)
    const int n = (y0 + yi) * Wn + x0 + xi;
    unsigned short* dst = &sT[((size_t)b * HWn + n) * Cn + kq * 32];
#pragma unroll
    for (int q = 0; q < 4; ++q) {
        unsigned pk[4];
#pragma unroll
        for (int e = 0; e < 4; ++e)
            pk[e] = (unsigned)f2bf(acc[q * 8 + 2 * e]) |
                    ((unsigned)f2bf(acc[q * 8 + 2 * e + 1]) << 16);
        uint4 v; v.x = pk[0]; v.y = pk[1]; v.z = pk[2]; v.w = pk[3];
        *(uint4*)&dst[q * 8] = v;
    }
}

// ---------------- K_V: out = fmap + g * Wv @ sT (verbatim R2-K2) ----------------
__global__ __launch_bounds__(256) void lsa_gemm(
    const unsigned short* __restrict__ sT, const unsigned short* __restrict__ wvb,
    const float* __restrict__ fmap, const float* __restrict__ gamma,
    float* __restrict__ out)
{
    const int tid = threadIdx.x;
    const int wave = tid >> 6, lane = tid & 63;
    const int m16 = lane & 15, q = lane >> 4;
    const int b = blockIdx.y;
    const int ntile = blockIdx.x * 32 + (wave >> 1) * 16;  // 16 px per wave
    const int mhalf = wave & 1;                            // 64 channels per wave
    const float g = gamma[0];

    short8 bfrag[4];
    const unsigned short* srow = &sT[((size_t)b * HWn + ntile + m16) * Cn + q * 8];
#pragma unroll
    for (int kk = 0; kk < 4; ++kk) bfrag[kk] = *(const short8*)(srow + kk * 32);

    f32x4 acc[4];
#pragma unroll
    for (int t = 0; t < 4; ++t) { f32x4 z = {0.f, 0.f, 0.f, 0.f}; acc[t] = z; }

#pragma unroll
    for (int t = 0; t < 4; ++t) {
        const int mg = mhalf * 4 + t;
        const unsigned short* arow = &wvb[(size_t)(mg * 16 + m16) * Cn + q * 8];
#pragma unroll
        for (int kk = 0; kk < 4; ++kk) {
            short8 af = *(const short8*)(arow + kk * 32);
            acc[t] = __builtin_amdgcn_mfma_f32_16x16x32_bf16(af, bfrag[kk], acc[t], 0, 0, 0);
        }
    }
#pragma unroll
    for (int t = 0; t < 4; ++t) {
        const int mg = mhalf * 4 + t;
#pragma unroll
        for (int r = 0; r < 4; ++r) {
            const int c = mg * 16 + q * 4 + r;
            const size_t idx = ((size_t)(b * Cn + c)) * HWn + ntile + m16;
            out[idx] = fmap[idx] + g * acc[t][r];
        }
    }
}
}  // namespace

extern "C" void kernel_launch(void* const* d_in, const int* in_sizes, int n_in,
                              void* d_out, int out_size, void* d_ws, size_t ws_size,
                              hipStream_t stream) {
    const float* attn  = (const float*)d_in[0];
    const float* fmap  = (const float*)d_in[1];
    const float* Wv    = (const float*)d_in[2];
    const float* gamma = (const float*)d_in[3];
    float* out = (float*)d_out;

    // ws layout: sT 8.39 MB | fT 8.39 MB | wvb 32 KB  (ws is ~268 MB per profile)
    unsigned short* sT  = (unsigned short*)d_ws;
    unsigned short* fT  = sT + (size_t)Bn * HWn * Cn;
    unsigned short* wvb = fT + (size_t)Bn * HWn * Cn;

    dim3 gT(HWn / 32, Bn);            // 256 x 4
    k_transpose<<<gT, 256, 0, stream>>>(fmap, Wv, fT, wvb);

    dim3 gS(Wn / TX, Hn / TY, Bn);    // 8 x 16 x 4
    k_stencil<<<gS, 256, 0, stream>>>(fT, attn, sT);

    dim3 gV(HWn / 32, Bn);            // 256 x 4
    lsa_gemm<<<gV, 256, 0, stream>>>(sT, wvb, fmap, gamma, out);
}